// Round 9
// baseline (244.794 us; speedup 1.0000x reference)
//
#include <hip/hip_runtime.h>
#include <hip/hip_bf16.h>
#include <math.h>

// ---- problem constants (MultiScaleRetention, B=2,T=2048,E=1024,V=2048,H=8) ----
constexpr int T_SEQ = 2048;
constexpr int BB    = 2;
constexpr int EMBED = 1024;
constexpr int VDIM  = 2048;
constexpr int NHEADS = 8;
constexpr int KDIM  = 128;
constexpr int HDIM  = 256;
constexpr int ROWS  = BB * T_SEQ;  // 4096
constexpr int NALL  = 6144;        // Q(1024)+K(1024)+V(2048)+G(2048)
constexpr float EPS = 1e-6f;

typedef float  f32x4  __attribute__((ext_vector_type(4)));
typedef __bf16 bf16x8 __attribute__((ext_vector_type(8)));
typedef __bf16 bf16x4 __attribute__((ext_vector_type(4)));

// async global->LDS, 16B per lane. LDS dest is wave-uniform base + lane*16;
// global src is per-lane. Drained by the vmcnt(0) the compiler emits before
// s_barrier (__syncthreads).
__device__ __forceinline__ void gload16(const void* g, void* l) {
    __builtin_amdgcn_global_load_lds(
        (__attribute__((address_space(1))) void*)g,
        (__attribute__((address_space(3))) void*)l, 16, 0, 0);
}

// ============================================================================
// f32 -> bf16 elementwise (vectorized: float4 in, bf16x4 out)
// ============================================================================
__global__ __launch_bounds__(256)
void f32_to_bf16(const float* __restrict__ in, __bf16* __restrict__ out, int n4) {
    int i = blockIdx.x * 256 + threadIdx.x;
    if (i < n4) {
        float4 v = reinterpret_cast<const float4*>(in)[i];
        bf16x4 o = { (__bf16)v.x, (__bf16)v.y, (__bf16)v.z, (__bf16)v.w };
        reinterpret_cast<bf16x4*>(out)[i] = o;
    }
}

// ============================================================================
// All five W[K][N] f32 -> WT[N][K] bf16 transposes in ONE launch.
// ============================================================================
__global__ __launch_bounds__(256)
void transpose_all(const float* __restrict__ Wq, const float* __restrict__ Wk,
                   const float* __restrict__ Wv, const float* __restrict__ Wg,
                   const float* __restrict__ Wo,
                   __bf16* __restrict__ WqT, __bf16* __restrict__ WkT,
                   __bf16* __restrict__ WvT, __bf16* __restrict__ WgT,
                   __bf16* __restrict__ WoT) {
    const int bid = blockIdx.x;
    const float* W; __bf16* WT; int K, N, cx, cy;
    if (bid < 1024)      { W = Wq; WT = WqT; K = 1024; N = 1024; int rm = bid;        cx = rm & 31; cy = rm >> 5; }
    else if (bid < 2048) { W = Wk; WT = WkT; K = 1024; N = 1024; int rm = bid - 1024; cx = rm & 31; cy = rm >> 5; }
    else if (bid < 4096) { W = Wv; WT = WvT; K = 1024; N = 2048; int rm = bid - 2048; cx = rm & 63; cy = rm >> 6; }
    else if (bid < 6144) { W = Wg; WT = WgT; K = 1024; N = 2048; int rm = bid - 4096; cx = rm & 63; cy = rm >> 6; }
    else                 { W = Wo; WT = WoT; K = 2048; N = 1024; int rm = bid - 6144; cx = rm & 31; cy = rm >> 5; }

    __shared__ float tile[32][33];
    const int c0 = cx * 32, k0 = cy * 32;
    const int x = threadIdx.x, y = threadIdx.y;
    #pragma unroll
    for (int p = 0; p < 4; ++p)
        tile[y + p * 8][x] = W[(size_t)(k0 + y + p * 8) * N + c0 + x];
    __syncthreads();
    #pragma unroll
    for (int p = 0; p < 4; ++p)
        WT[(size_t)(c0 + y + p * 8) * K + k0 + x] = (__bf16)tile[x][y + p * 8];
}

// ============================================================================
// Fused QKVG projection GEMM (R7 measured-best): C = xb @ WTall^T, routed.
// - Q/K: kscale folded, theta-shift (RoPE) in epilogue via shfl_xor.
// - V:   written DIRECTLY TRANSPOSED to Vt[b][h][d][t] via per-wave LDS turn.
// - G:   plain bf16 row-major.
// m97 2-barrier structure, 128x128 tile, BK=32, global_load_lds + XOR swizzle,
// 1D grid 1536 with row-pinned XCD swizzle.
// ============================================================================
__global__ __launch_bounds__(256)
void gemm_qkvg(const __bf16* __restrict__ A, const __bf16* __restrict__ BT,
               __bf16* __restrict__ Qb, __bf16* __restrict__ Kb,
               __bf16* __restrict__ Vt, __bf16* __restrict__ Gb,
               const float* __restrict__ sinT, const float* __restrict__ cosT) {
    constexpr int K = EMBED;
    // union: staging As+Bs (16KB) | epilogue transpose Es (4 waves x 64x72 bf16)
    __shared__ __align__(16) char smem[4 * 64 * 72 * 2];  // 36864 B
    __bf16* As = (__bf16*)smem;              // [128][32] linear
    __bf16* Bs = (__bf16*)(smem + 8192);     // [128][32] linear

    // XCD swizzle: 1536 = 8 * 192 -> XCD k covers rows 4k..4k+3, all 48 cols
    const int bid = blockIdx.x;
    const int swzb = (bid & 7) * 192 + (bid >> 3);
    const int rowBase = (swzb / 48) * 128;
    const int colBase = (swzb % 48) * 128;

    const int tid = threadIdx.x;
    const int w = tid >> 6, lane = tid & 63;
    const int g = lane >> 4, r = lane & 15;
    const int wm = w >> 1, wn = w & 1;

    const int swz = ((lane & 3) ^ ((lane >> 3) & 3)) * 8;
    const int lr  = lane >> 2;
    const __bf16* aS0 = A  + (size_t)(rowBase + 32 * w      + lr) * K + swz;
    const __bf16* aS1 = A  + (size_t)(rowBase + 32 * w + 16 + lr) * K + swz;
    const __bf16* bS0 = BT + (size_t)(colBase + 32 * w      + lr) * K + swz;
    const __bf16* bS1 = BT + (size_t)(colBase + 32 * w + 16 + lr) * K + swz;
    char* aD0 = smem        + (2 * w    ) * 1024;
    char* aD1 = smem        + (2 * w + 1) * 1024;
    char* bD0 = smem + 8192 + (2 * w    ) * 1024;
    char* bD1 = smem + 8192 + (2 * w + 1) * 1024;

    const int colR = (g ^ ((r >> 1) & 3)) * 8;

    f32x4 acc[4][4];
    #pragma unroll
    for (int i = 0; i < 4; ++i)
        #pragma unroll
        for (int j = 0; j < 4; ++j)
            acc[i][j] = (f32x4){0.f, 0.f, 0.f, 0.f};

    for (int k0 = 0; k0 < K; k0 += 32) {
        __syncthreads();            // previous compute done
        gload16(aS0 + k0, aD0);
        gload16(aS1 + k0, aD1);
        gload16(bS0 + k0, bD0);
        gload16(bS1 + k0, bD1);
        __syncthreads();            // vmcnt(0) drained by compiler

        bf16x8 bfrag[4];
        #pragma unroll
        for (int nf = 0; nf < 4; ++nf)
            bfrag[nf] = *reinterpret_cast<const bf16x8*>(
                &Bs[(wn * 64 + nf * 16 + r) * 32 + colR]);
        #pragma unroll
        for (int mf = 0; mf < 4; ++mf) {
            bf16x8 a = *reinterpret_cast<const bf16x8*>(
                &As[(wm * 64 + mf * 16 + r) * 32 + colR]);
            #pragma unroll
            for (int nf = 0; nf < 4; ++nf)
                acc[mf][nf] = __builtin_amdgcn_mfma_f32_16x16x32_bf16(a, bfrag[nf], acc[mf][nf], 0, 0, 0);
        }
    }

    // ---- segment routing (block-uniform) ----
    constexpr float kscale = 0.08838834764831845f;  // KEY_DIM^-0.5
    if (colBase >= 2048 && colBase < 4096) {
        // ========== V segment: transposed write to Vt[b][h][d][t] ==========
        __syncthreads();  // all waves done reading As/Bs before Es overwrites
        __bf16* Es = (__bf16*)smem + w * (64 * 72);  // [d64][t72] per wave
        #pragma unroll
        for (int mf = 0; mf < 4; ++mf)
            #pragma unroll
            for (int nf = 0; nf < 4; ++nf) {
                bf16x4 v = { (__bf16)acc[mf][nf][0], (__bf16)acc[mf][nf][1],
                             (__bf16)acc[mf][nf][2], (__bf16)acc[mf][nf][3] };
                *reinterpret_cast<bf16x4*>(&Es[(nf * 16 + r) * 72 + mf * 16 + g * 4]) = v;
            }
        __syncthreads();
        const int t0g = rowBase + wm * 64;
        const int bq = t0g >> 11, tl = t0g & 2047;
        const int colV0 = (colBase - 2048) + wn * 64;
        const int h = colV0 >> 8, dd0 = colV0 & 255;
        const int li = lane & 7, rgrp = lane >> 3;
        __bf16* vtb = Vt + ((size_t)(bq * NHEADS + h) * HDIM + dd0) * T_SEQ + tl;
        #pragma unroll
        for (int c = 0; c < 8; ++c) {
            const int drow = 8 * c + rgrp;
            bf16x8 v = *reinterpret_cast<const bf16x8*>(&Es[drow * 72 + li * 8]);
            *reinterpret_cast<bf16x8*>(vtb + (size_t)drow * T_SEQ + li * 8) = v;
        }
        return;
    }

    __bf16* dst; int dstride, cofs; float alphaSeg; bool rot;
    if (colBase < 1024)      { dst = Qb; dstride = 1024; cofs = colBase;        alphaSeg = 1.0f;   rot = true;  }
    else if (colBase < 2048) { dst = Kb; dstride = 1024; cofs = colBase - 1024; alphaSeg = kscale; rot = true;  }
    else                     { dst = Gb; dstride = 2048; cofs = colBase - 4096; alphaSeg = 1.0f;   rot = false; }

    // epilogue: C/D layout col = lane&15, row = (lane>>4)*4 + reg
    #pragma unroll
    for (int mf = 0; mf < 4; ++mf)
        #pragma unroll
        for (int nf = 0; nf < 4; ++nf)
            #pragma unroll
            for (int j = 0; j < 4; ++j) {
                const int row  = rowBase + wm * 64 + mf * 16 + g * 4 + j;
                const int colL = cofs + wn * 64 + nf * 16 + r;
                float v = acc[mf][nf][j] * alphaSeg;
                if (rot) {
                    const float p = __shfl_xor(v, 1);   // value at column colL^1
                    const int t  = row & (T_SEQ - 1);
                    const int dh = colL & (KDIM - 1);
                    const float c = cosT[t * KDIM + dh];
                    const float s = sinT[t * KDIM + dh];
                    v = (r & 1) ? (v * c + p * s) : (v * c - p * s);
                }
                dst[(size_t)row * dstride + colL] = (__bf16)v;
            }
}

// ============================================================================
// Output projection (R7): C[4096][1024] f32 = Yb @ WoT^T. 64x128 tile, BK=32,
// 2-barrier m97 structure, row-pinned XCD swizzle.
// ============================================================================
__global__ __launch_bounds__(256)
void gemm_wo(const __bf16* __restrict__ A, const __bf16* __restrict__ BT,
             float* __restrict__ C) {
    constexpr int N = EMBED, K = VDIM;
    __shared__ __align__(16) __bf16 As[64 * 32];    // 4KB
    __shared__ __align__(16) __bf16 Bs[128 * 32];   // 8KB

    const int bid = blockIdx.x;
    const int swzb = (bid & 7) * 64 + (bid >> 3);
    const int rowBase = (swzb >> 3) * 64;
    const int colBase = (swzb & 7) * 128;

    const int tid = threadIdx.x;
    const int w = tid >> 6, lane = tid & 63;
    const int g = lane >> 4, r = lane & 15;
    const int wm = w >> 1, wn = w & 1;

    const int swz = ((lane & 3) ^ ((lane >> 3) & 3)) * 8;
    const int lr  = lane >> 2;
    const __bf16* aS  = A  + (size_t)(rowBase + 16 * w + lr) * K + swz;
    const __bf16* bS0 = BT + (size_t)(colBase + 32 * w      + lr) * K + swz;
    const __bf16* bS1 = BT + (size_t)(colBase + 32 * w + 16 + lr) * K + swz;
    char* aD  = (char*)&As[0] + w * 1024;
    char* bD0 = (char*)&Bs[0] + (2 * w    ) * 1024;
    char* bD1 = (char*)&Bs[0] + (2 * w + 1) * 1024;

    const int colR = (g ^ ((r >> 1) & 3)) * 8;

    f32x4 acc[2][4];
    #pragma unroll
    for (int i = 0; i < 2; ++i)
        #pragma unroll
        for (int j = 0; j < 4; ++j)
            acc[i][j] = (f32x4){0.f, 0.f, 0.f, 0.f};

    for (int k0 = 0; k0 < K; k0 += 32) {
        __syncthreads();
        gload16(aS  + k0, aD);
        gload16(bS0 + k0, bD0);
        gload16(bS1 + k0, bD1);
        __syncthreads();

        bf16x8 bfrag[4];
        #pragma unroll
        for (int nf = 0; nf < 4; ++nf)
            bfrag[nf] = *reinterpret_cast<const bf16x8*>(
                &Bs[(wn * 64 + nf * 16 + r) * 32 + colR]);
        #pragma unroll
        for (int mf = 0; mf < 2; ++mf) {
            bf16x8 a = *reinterpret_cast<const bf16x8*>(
                &As[(wm * 32 + mf * 16 + r) * 32 + colR]);
            #pragma unroll
            for (int nf = 0; nf < 4; ++nf)
                acc[mf][nf] = __builtin_amdgcn_mfma_f32_16x16x32_bf16(a, bfrag[nf], acc[mf][nf], 0, 0, 0);
        }
    }

    #pragma unroll
    for (int mf = 0; mf < 2; ++mf)
        #pragma unroll
        for (int nf = 0; nf < 4; ++nf)
            #pragma unroll
            for (int j = 0; j < 4; ++j) {
                const int row = rowBase + wm * 32 + mf * 16 + g * 4 + j;
                const int col = colBase + wn * 64 + nf * 16 + r;
                C[(size_t)row * N + col] = acc[mf][nf][j];
            }
}

// ============================================================================
// MFMA retention, LDS-BW-optimized PV. Block = 64 q-rows; 4 waves.
// QK phase (unchanged, proven): wave w owns q-rows [16w,16w+16), computes
// P[its rows][all 64 s] -> SHARED Ps[64][72], plus per-row dsum (complete).
// PV phase (NEW 4x4 outer product): wave w owns d-cols [64w, 64w+64) x ALL
// 64 q-rows: reads 8 pf + 8 vf per iter (was 2+32) -> block LDS reads drop
// ~200KB -> ~128KB per iter (retention is LDS-read-BW bound: R4 PMC).
// Epilogue: dsum via LDS broadcast; RMS-ss via 4-partial cross-wave reduce.
// ============================================================================
__global__ __launch_bounds__(256)
void retention_mfma(const __bf16* __restrict__ Qb, const __bf16* __restrict__ Kb,
                    const __bf16* __restrict__ Vt,
                    const __bf16* __restrict__ Gb, __bf16* __restrict__ Yb) {
    const int tid = threadIdx.x;
    const int w = tid >> 6, lane = tid & 63;
    const int g = lane >> 4, r = lane & 15;
    const int rx = r & 7;
    const int bid = blockIdx.x;
    const int h = bid & 7;
    const int slot = bid >> 3;
    const int b = slot & 1;
    const int x = slot >> 1;
    const int qt = (b == 0) ? (31 - x) : x;
    const int tt0 = qt * 64;
    const int trow0 = w * 16;

    __shared__ __align__(16) __bf16 Ks[64][128];   // linear, swizzled content
    __shared__ __align__(16) __bf16 Vs[256][64];   // linear, swizzled content
    __shared__ __align__(16) __bf16 Ps[64][72];    // SHARED P tile, +8 pad
    __shared__ float dsumL[64];
    __shared__ float ssL[4][64];

    // ---- decay constants (mask on the fly) ----
    const float rho   = 1.0f - exp2f(-(float)(5 + h));
    const float l2r   = log2f(rho);
    const float inv1m = exp2f((float)(5 + h));      // 1/(1-rho)
    int   tj[4];
    float nrm[4];
    #pragma unroll
    for (int j = 0; j < 4; ++j) {
        tj[j] = tt0 + trow0 + g * 4 + j;
        nrm[j] = rsqrtf((1.0f - exp2f(l2r * (float)(tj[j] + 1))) * inv1m);
    }
    float pneg[4];                                  // rho^(-(ssub*16+r))
    #pragma unroll
    for (int ssub = 0; ssub < 4; ++ssub)
        pneg[ssub] = exp2f(-l2r * (float)(ssub * 16 + r));

    // Q fragments: wave's 16 q-rows x 128 k, persistent in registers
    bf16x8 qf[4];
    {
        const __bf16* qrow = Qb + ((size_t)(b * T_SEQ + tt0 + trow0 + r)) * EMBED + h * KDIM;
        #pragma unroll
        for (int kb = 0; kb < 4; ++kb)
            qf[kb] = *reinterpret_cast<const bf16x8*>(qrow + kb * 32 + g * 8);
    }

    // PV accumulator: [qsub][dsub] -> q = qsub*16+g*4+j, d = w*64+dsub*16+r
    f32x4 acc[4][4];
    #pragma unroll
    for (int qs = 0; qs < 4; ++qs)
        #pragma unroll
        for (int ds = 0; ds < 4; ++ds)
            acc[qs][ds] = (f32x4){0.f, 0.f, 0.f, 0.f};
    float dsum[4] = {0.f, 0.f, 0.f, 0.f};

    const __bf16* vtbase = Vt + ((size_t)(b * NHEADS + h) * HDIM) * T_SEQ;
    const __bf16* kbase  = Kb + ((size_t)(b * T_SEQ)) * EMBED + h * KDIM;

    // staging maps (per-lane source offsets)
    const int klr = lane >> 4;                      // K: row within 4-row call
    const int kc  = lane & 15;
    const int kswz_even = (kc ^ klr) * 8;           // cc even
    const int kswz_odd  = (kc ^ (4 + klr)) * 8;     // cc odd
    const int vlr  = lane >> 3;                     // V: row within 8-row call
    const int vswz = ((lane & 7) ^ vlr) * 8;

    const int nS = qt + 1;
    for (int st = 0; st < nS; ++st) {
        const int ss0 = st * 64;
        __syncthreads();  // previous tile's LDS reads complete
        // ---- K s-tile 64x128: 16 calls (4/wave)
        #pragma unroll
        for (int p = 0; p < 4; ++p) {
            const int cc = 4 * w + p;
            const int se = (p & 1) ? kswz_odd : kswz_even;
            gload16(kbase + (size_t)(ss0 + 4 * cc + klr) * EMBED + se,
                    (char*)&Ks[0][0] + cc * 1024);
        }
        // ---- V^T s-tile 256x64: 32 calls (8/wave)
        #pragma unroll
        for (int p = 0; p < 8; ++p) {
            const int cc = 8 * w + p;
            gload16(vtbase + (size_t)(8 * cc + vlr) * T_SEQ + ss0 + vswz,
                    (char*)&Vs[0][0] + cc * 1024);
        }
        __syncthreads();  // all gload_lds writes landed (vmcnt drain)

        // per-tile decay factors
        float wj[4];
        #pragma unroll
        for (int j = 0; j < 4; ++j)
            wj[j] = exp2f(l2r * (float)(tj[j] - ss0)) * nrm[j];
        const bool diag = (st == qt);

        // ---- QK^T + mask + dsum + P -> shared Ps ----
        #pragma unroll
        for (int ssub = 0; ssub < 4; ++ssub) {
            f32x4 sacc = (f32x4){0.f, 0.f, 0.f, 0.f};
            #pragma unroll
            for (int kb = 0; kb < 4; ++kb) {
                bf16x8 kf = *reinterpret_cast<const bf16x8*>(
                    &Ks[ssub * 16 + r][((kb * 4 + g) ^ rx) * 8]);
                sacc = __builtin_amdgcn_mfma_f32_16x16x32_bf16(qf[kb], kf, sacc, 0, 0, 0);
            }
            const int scol = ss0 + ssub * 16 + r;
            const float mfac = pneg[ssub];
            #pragma unroll
            for (int j = 0; j < 4; ++j) {
                float pv = sacc[j] * (wj[j] * mfac);
                if (diag && scol > tj[j]) pv = 0.f;
                dsum[j] += fabsf(pv);
                Ps[trow0 + g * 4 + j][ssub * 16 + r] = (__bf16)pv;
            }
        }
        __syncthreads();  // Ps published to all waves

        // ---- PV 4x4: acc[qs][ds] += P(64q x 64s) @ V^T slice (64d x 64s) ----
        #pragma unroll
        for (int sh = 0; sh < 2; ++sh) {
            bf16x8 pf[4];
            #pragma unroll
            for (int qs = 0; qs < 4; ++qs)
                pf[qs] = *reinterpret_cast<const bf16x8*>(
                    &Ps[qs * 16 + r][sh * 32 + g * 8]);
            #pragma unroll
            for (int ds = 0; ds < 4; ++ds) {
                bf16x8 vf = *reinterpret_cast<const bf16x8*>(
                    &Vs[w * 64 + ds * 16 + r][((sh * 4 + g) ^ rx) * 8]);
                #pragma unroll
                for (int qs = 0; qs < 4; ++qs)
                    acc[qs][ds] = __builtin_amdgcn_mfma_f32_16x16x32_bf16(pf[qs], vf, acc[qs][ds], 0, 0, 0);
            }
        }
    }

    // ---- epilogue ----
    // 1) finalize per-row dsum (this wave's 16 rows), publish to LDS
    #pragma unroll
    for (int j = 0; j < 4; ++j) {
        float v = dsum[j];
        v += __shfl_xor(v, 1); v += __shfl_xor(v, 2);
        v += __shfl_xor(v, 4); v += __shfl_xor(v, 8);
        dsum[j] = fminf(fmaxf(v, 1.0f), 50000.0f);
    }
    if (r == 0) {
        #pragma unroll
        for (int j = 0; j < 4; ++j)
            dsumL[trow0 + g * 4 + j] = dsum[j];
    }
    __syncthreads();

    // 2) divide by denom; RMS partials over this wave's 64 d-cols
    #pragma unroll
    for (int qs = 0; qs < 4; ++qs)
        #pragma unroll
        for (int j = 0; j < 4; ++j) {
            const float inv = 1.0f / dsumL[qs * 16 + g * 4 + j];
            float sp = 0.f;
            #pragma unroll
            for (int ds = 0; ds < 4; ++ds) {
                const float v = acc[qs][ds][j] * inv;
                acc[qs][ds][j] = v;
                sp = fmaf(v, v, sp);
            }
            sp += __shfl_xor(sp, 1); sp += __shfl_xor(sp, 2);
            sp += __shfl_xor(sp, 4); sp += __shfl_xor(sp, 8);
            if (r == 0) ssL[w][qs * 16 + g * 4 + j] = sp;
        }
    __syncthreads();

    // 3) total RMS, silu(g) gate, write Y (wave w writes cols [64w, 64w+64))
    #pragma unroll
    for (int qs = 0; qs < 4; ++qs)
        #pragma unroll
        for (int j = 0; j < 4; ++j) {
            const int ql = qs * 16 + g * 4 + j;
            const float tot = ssL[0][ql] + ssL[1][ql] + ssL[2][ql] + ssL[3][ql];
            const float rs = rsqrtf(tot * (1.0f / 256.0f) + EPS);
            const size_t row = (size_t)(b * T_SEQ + tt0 + ql);
            const __bf16* grow = Gb + row * VDIM + h * HDIM;
            __bf16* yrow = Yb + row * VDIM + h * HDIM;
            #pragma unroll
            for (int ds = 0; ds < 4; ++ds) {
                const int c = w * 64 + ds * 16 + r;
                const float gv = (float)grow[c];
                const float sil = gv / (1.0f + expf(-gv));
                yrow[c] = (__bf16)(sil * acc[qs][ds][j] * rs);
            }
        }
}

// ============================================================================
// launch
// ============================================================================
extern "C" void kernel_launch(void* const* d_in, const int* in_sizes, int n_in,
                              void* d_out, int out_size, void* d_ws, size_t ws_size,
                              hipStream_t stream) {
    (void)in_sizes; (void)n_in; (void)out_size; (void)ws_size;

    const float* x    = (const float*)d_in[0];
    const float* sinT = (const float*)d_in[1];
    const float* cosT = (const float*)d_in[2];
    // d_in[3] (mask) is recomputed on the fly in retention_mfma
    const float* Wq   = (const float*)d_in[4];
    const float* Wk   = (const float*)d_in[5];
    const float* Wv   = (const float*)d_in[6];
    const float* Wg   = (const float*)d_in[7];
    const float* Wo   = (const float*)d_in[8];
    float* out = (float*)d_out;

    // workspace layout (bytes), peak 88 MB. WqT..WgT are CONTIGUOUS -> one
    // packed [6144][1024] weight matrix for the fused projection GEMM.
    char* wsp = (char*)d_ws;
    __bf16* xb  = (__bf16*)(wsp);
    __bf16* WqT = (__bf16*)(wsp + (8u  << 20));
    __bf16* WkT = (__bf16*)(wsp + (10u << 20));
    __bf16* WvT = (__bf16*)(wsp + (12u << 20));
    __bf16* WgT = (__bf16*)(wsp + (16u << 20));
    __bf16* WoT = (__bf16*)(wsp + (20u << 20));
    __bf16* Qb  = (__bf16*)(wsp + (24u << 20));
    __bf16* Kb  = (__bf16*)(wsp + (32u << 20));
    __bf16* Yb  = (__bf16*)(wsp + (40u << 20));  // retention output (gated)
    __bf16* Gb  = (__bf16*)(wsp + (56u << 20));
    __bf16* Vt  = (__bf16*)(wsp + (72u << 20));
    __bf16* WTall = WqT;                         // packed Q|K|V|G weights

    const dim3 blk(256);
    const dim3 tblk(32, 8);

    // ---- prep ----
    f32_to_bf16<<<(ROWS * EMBED / 4) / 256, blk, 0, stream>>>(x, xb, ROWS * EMBED / 4);
    transpose_all<<<8192, tblk, 0, stream>>>(Wq, Wk, Wv, Wg, Wo, WqT, WkT, WvT, WgT, WoT);

    // ---- fused QKVG projection (rotation + kscale + V-transpose in epilogue)
    gemm_qkvg<<<1536, blk, 0, stream>>>(xb, WTall, Qb, Kb, Vt, Gb, sinT, cosT);

    // ---- fused retention (MFMA, mask on the fly, XCD-pinned, 4x4 PV) ----
    retention_mfma<<<512, blk, 0, stream>>>(Qb, Kb, Vt, Gb, Yb);

    // ---- output projection ----
    gemm_wo<<<512, blk, 0, stream>>>(Yb, WoT, out);
}

// Round 10
// 194.686 us; speedup vs baseline: 1.2574x; 1.2574x over previous
//
#include <hip/hip_runtime.h>
#include <hip/hip_bf16.h>
#include <math.h>

// ---- problem constants (MultiScaleRetention, B=2,T=2048,E=1024,V=2048,H=8) ----
constexpr int T_SEQ = 2048;
constexpr int BB    = 2;
constexpr int EMBED = 1024;
constexpr int VDIM  = 2048;
constexpr int NHEADS = 8;
constexpr int KDIM  = 128;
constexpr int HDIM  = 256;
constexpr int ROWS  = BB * T_SEQ;  // 4096
constexpr int NALL  = 6144;        // Q(1024)+K(1024)+V(2048)+G(2048)
constexpr float EPS = 1e-6f;

typedef float  f32x4  __attribute__((ext_vector_type(4)));
typedef __bf16 bf16x8 __attribute__((ext_vector_type(8)));
typedef __bf16 bf16x4 __attribute__((ext_vector_type(4)));

// async global->LDS, 16B per lane. LDS dest is wave-uniform base + lane*16;
// global src is per-lane. Drained by the vmcnt(0) the compiler emits before
// s_barrier (__syncthreads).
__device__ __forceinline__ void gload16(const void* g, void* l) {
    __builtin_amdgcn_global_load_lds(
        (__attribute__((address_space(1))) void*)g,
        (__attribute__((address_space(3))) void*)l, 16, 0, 0);
}

// ============================================================================
// Merged prep: five W[K][N] f32 -> WT[N][K] bf16 transposes (bid < 8192)
// + x f32->bf16 convert (bid >= 8192). One launch.
// ============================================================================
__global__ __launch_bounds__(256)
void prep_all(const float* __restrict__ x, const float* __restrict__ Wq,
              const float* __restrict__ Wk, const float* __restrict__ Wv,
              const float* __restrict__ Wg, const float* __restrict__ Wo,
              __bf16* __restrict__ xb,
              __bf16* __restrict__ WqT, __bf16* __restrict__ WkT,
              __bf16* __restrict__ WvT, __bf16* __restrict__ WgT,
              __bf16* __restrict__ WoT) {
    const int bid = blockIdx.x;
    const int x_ = threadIdx.x, y_ = threadIdx.y;
    if (bid >= 8192) {
        // ---- f32 -> bf16 convert: 4096 blocks x 256 threads x 4 elems ----
        const int i = (bid - 8192) * 256 + y_ * 32 + x_;
        float4 v = reinterpret_cast<const float4*>(x)[i];
        bf16x4 o = { (__bf16)v.x, (__bf16)v.y, (__bf16)v.z, (__bf16)v.w };
        reinterpret_cast<bf16x4*>(xb)[i] = o;
        return;
    }
    const float* W; __bf16* WT; int K, N, cx, cy;
    if (bid < 1024)      { W = Wq; WT = WqT; K = 1024; N = 1024; int rm = bid;        cx = rm & 31; cy = rm >> 5; }
    else if (bid < 2048) { W = Wk; WT = WkT; K = 1024; N = 1024; int rm = bid - 1024; cx = rm & 31; cy = rm >> 5; }
    else if (bid < 4096) { W = Wv; WT = WvT; K = 1024; N = 2048; int rm = bid - 2048; cx = rm & 63; cy = rm >> 6; }
    else if (bid < 6144) { W = Wg; WT = WgT; K = 1024; N = 2048; int rm = bid - 4096; cx = rm & 63; cy = rm >> 6; }
    else                 { W = Wo; WT = WoT; K = 2048; N = 1024; int rm = bid - 6144; cx = rm & 31; cy = rm >> 5; }

    __shared__ float tile[32][33];
    const int c0 = cx * 32, k0 = cy * 32;
    #pragma unroll
    for (int p = 0; p < 4; ++p)
        tile[y_ + p * 8][x_] = W[(size_t)(k0 + y_ + p * 8) * N + c0 + x_];
    __syncthreads();
    #pragma unroll
    for (int p = 0; p < 4; ++p)
        WT[(size_t)(c0 + y_ + p * 8) * K + k0 + x_] = (__bf16)tile[x_][y_ + p * 8];
}

// ============================================================================
// Fused QKVG projection GEMM: C = xb @ WTall^T, segment-routed.
// - Q/K: kscale folded, theta-shift (RoPE) in epilogue via shfl_xor.
// - V:   written DIRECTLY TRANSPOSED to Vt[b][h][d][t] via per-wave LDS turn.
// - G:   plain bf16 row-major.
// m97 2-barrier structure, 128x128 tile, BK=64 (halves vmcnt-drain count vs
// BK=32; LDS 32KB keeps occupancy). G4 swizzle for 128B rows: LDS[row][c] =
// G[row][c ^ (row&7)] (16B chunks); source chunk (lane&7)^(lane>>3), read
// chunk (kk*4+g)^(r&7). 1D grid 1536, row-pinned XCD swizzle (measured best).
// ============================================================================
__global__ __launch_bounds__(256)
void gemm_qkvg(const __bf16* __restrict__ A, const __bf16* __restrict__ BT,
               __bf16* __restrict__ Qb, __bf16* __restrict__ Kb,
               __bf16* __restrict__ Vt, __bf16* __restrict__ Gb,
               const float* __restrict__ sinT, const float* __restrict__ cosT) {
    constexpr int K = EMBED;
    // union: staging As(16K)+Bs(16K) | epilogue transpose Es (4 x 64x72 bf16)
    __shared__ __align__(16) char smem[36864];
    __bf16* As = (__bf16*)smem;               // [128][64] linear, swizzled
    __bf16* Bs = (__bf16*)(smem + 16384);     // [128][64] linear, swizzled

    // XCD swizzle: 1536 = 8 * 192 -> XCD k covers rows 4k..4k+3, all 48 cols
    const int bid = blockIdx.x;
    const int swzb = (bid & 7) * 192 + (bid >> 3);
    const int rowBase = (swzb / 48) * 128;
    const int colBase = (swzb % 48) * 128;

    const int tid = threadIdx.x;
    const int w = tid >> 6, lane = tid & 63;
    const int g = lane >> 4, r = lane & 15;
    const int wm = w >> 1, wn = w & 1;

    // staging maps: call cc covers rows 8cc..8cc+7 (128B/row); per-lane row
    // vr = lane>>3, source chunk = (lane&7) ^ vr (involution with read side)
    const int vr  = lane >> 3;
    const int swz = ((lane & 7) ^ vr) * 8;    // source elem offset in 64-col slice
    const __bf16* aSb = A  + (size_t)(rowBase + 32 * w + vr) * K + swz;
    const __bf16* bSb = BT + (size_t)(colBase + 32 * w + vr) * K + swz;

    f32x4 acc[4][4];
    #pragma unroll
    for (int i = 0; i < 4; ++i)
        #pragma unroll
        for (int j = 0; j < 4; ++j)
            acc[i][j] = (f32x4){0.f, 0.f, 0.f, 0.f};

    for (int k0 = 0; k0 < K; k0 += 64) {
        __syncthreads();            // previous compute done
        #pragma unroll
        for (int p = 0; p < 4; ++p) {
            const int cc = 4 * w + p;
            gload16(aSb + (size_t)(8 * p) * K + k0, smem         + cc * 1024);
            gload16(bSb + (size_t)(8 * p) * K + k0, smem + 16384 + cc * 1024);
        }
        __syncthreads();            // vmcnt(0) drained by compiler

        #pragma unroll
        for (int kk = 0; kk < 2; ++kk) {
            bf16x8 bfrag[4];
            #pragma unroll
            for (int nf = 0; nf < 4; ++nf) {
                const int row = wn * 64 + nf * 16 + r;
                bfrag[nf] = *reinterpret_cast<const bf16x8*>(
                    &Bs[row * 64 + (((kk << 2) + g) ^ (r & 7)) * 8]);
            }
            #pragma unroll
            for (int mf = 0; mf < 4; ++mf) {
                const int row = wm * 64 + mf * 16 + r;
                bf16x8 a = *reinterpret_cast<const bf16x8*>(
                    &As[row * 64 + (((kk << 2) + g) ^ (r & 7)) * 8]);
                #pragma unroll
                for (int nf = 0; nf < 4; ++nf)
                    acc[mf][nf] = __builtin_amdgcn_mfma_f32_16x16x32_bf16(a, bfrag[nf], acc[mf][nf], 0, 0, 0);
            }
        }
    }

    // ---- segment routing (block-uniform) ----
    constexpr float kscale = 0.08838834764831845f;  // KEY_DIM^-0.5
    if (colBase >= 2048 && colBase < 4096) {
        // ========== V segment: transposed write to Vt[b][h][d][t] ==========
        __syncthreads();  // all waves done reading As/Bs before Es overwrites
        __bf16* Es = (__bf16*)smem + w * (64 * 72);  // [d64][t72] per wave
        #pragma unroll
        for (int mf = 0; mf < 4; ++mf)
            #pragma unroll
            for (int nf = 0; nf < 4; ++nf) {
                bf16x4 v = { (__bf16)acc[mf][nf][0], (__bf16)acc[mf][nf][1],
                             (__bf16)acc[mf][nf][2], (__bf16)acc[mf][nf][3] };
                *reinterpret_cast<bf16x4*>(&Es[(nf * 16 + r) * 72 + mf * 16 + g * 4]) = v;
            }
        __syncthreads();
        const int t0g = rowBase + wm * 64;
        const int bq = t0g >> 11, tl = t0g & 2047;
        const int colV0 = (colBase - 2048) + wn * 64;
        const int h = colV0 >> 8, dd0 = colV0 & 255;
        const int li = lane & 7, rgrp = lane >> 3;
        __bf16* vtb = Vt + ((size_t)(bq * NHEADS + h) * HDIM + dd0) * T_SEQ + tl;
        #pragma unroll
        for (int c = 0; c < 8; ++c) {
            const int drow = 8 * c + rgrp;
            bf16x8 v = *reinterpret_cast<const bf16x8*>(&Es[drow * 72 + li * 8]);
            *reinterpret_cast<bf16x8*>(vtb + (size_t)drow * T_SEQ + li * 8) = v;
        }
        return;
    }

    __bf16* dst; int dstride, cofs; float alphaSeg; bool rot;
    if (colBase < 1024)      { dst = Qb; dstride = 1024; cofs = colBase;        alphaSeg = 1.0f;   rot = true;  }
    else if (colBase < 2048) { dst = Kb; dstride = 1024; cofs = colBase - 1024; alphaSeg = kscale; rot = true;  }
    else                     { dst = Gb; dstride = 2048; cofs = colBase - 4096; alphaSeg = 1.0f;   rot = false; }

    // epilogue: C/D layout col = lane&15, row = (lane>>4)*4 + reg
    #pragma unroll
    for (int mf = 0; mf < 4; ++mf)
        #pragma unroll
        for (int nf = 0; nf < 4; ++nf)
            #pragma unroll
            for (int j = 0; j < 4; ++j) {
                const int row  = rowBase + wm * 64 + mf * 16 + g * 4 + j;
                const int colL = cofs + wn * 64 + nf * 16 + r;
                float v = acc[mf][nf][j] * alphaSeg;
                if (rot) {
                    const float p = __shfl_xor(v, 1);   // value at column colL^1
                    const int t  = row & (T_SEQ - 1);
                    const int dh = colL & (KDIM - 1);
                    const float c = cosT[t * KDIM + dh];
                    const float s = sinT[t * KDIM + dh];
                    v = (r & 1) ? (v * c + p * s) : (v * c - p * s);
                }
                dst[(size_t)row * dstride + colL] = (__bf16)v;
            }
}

// ============================================================================
// Output projection: C[4096][1024] f32 = Yb @ WoT^T. 64x128 tile, BK=64,
// 2-barrier m97 structure, row-pinned XCD swizzle, G4 swizzle as qkvg.
// ============================================================================
__global__ __launch_bounds__(256)
void gemm_wo(const __bf16* __restrict__ A, const __bf16* __restrict__ BT,
             float* __restrict__ C) {
    constexpr int N = EMBED, K = VDIM;
    __shared__ __align__(16) char smem[24576];
    __bf16* As = (__bf16*)smem;               // [64][64]  linear, swizzled
    __bf16* Bs = (__bf16*)(smem + 8192);      // [128][64] linear, swizzled

    const int bid = blockIdx.x;
    const int swzb = (bid & 7) * 64 + (bid >> 3);
    const int rowBase = (swzb >> 3) * 64;
    const int colBase = (swzb & 7) * 128;

    const int tid = threadIdx.x;
    const int w = tid >> 6, lane = tid & 63;
    const int g = lane >> 4, r = lane & 15;
    const int wm = w >> 1, wn = w & 1;

    const int vr  = lane >> 3;
    const int swz = ((lane & 7) ^ vr) * 8;
    const __bf16* aSb = A  + (size_t)(rowBase + 16 * w + vr) * K + swz;
    const __bf16* bSb = BT + (size_t)(colBase + 32 * w + vr) * K + swz;

    f32x4 acc[2][4];
    #pragma unroll
    for (int i = 0; i < 2; ++i)
        #pragma unroll
        for (int j = 0; j < 4; ++j)
            acc[i][j] = (f32x4){0.f, 0.f, 0.f, 0.f};

    for (int k0 = 0; k0 < K; k0 += 64) {
        __syncthreads();
        #pragma unroll
        for (int p = 0; p < 2; ++p) {  // A: 8 calls total, 2/wave
            const int cc = 2 * w + p;
            gload16(aSb + (size_t)(8 * p) * K + k0, smem + cc * 1024);
        }
        #pragma unroll
        for (int p = 0; p < 4; ++p) {  // B: 16 calls total, 4/wave
            const int cc = 4 * w + p;
            gload16(bSb + (size_t)(8 * p) * K + k0, smem + 8192 + cc * 1024);
        }
        __syncthreads();

        #pragma unroll
        for (int kk = 0; kk < 2; ++kk) {
            bf16x8 bfrag[4];
            #pragma unroll
            for (int nf = 0; nf < 4; ++nf) {
                const int row = wn * 64 + nf * 16 + r;
                bfrag[nf] = *reinterpret_cast<const bf16x8*>(
                    &Bs[row * 64 + (((kk << 2) + g) ^ (r & 7)) * 8]);
            }
            #pragma unroll
            for (int mf = 0; mf < 2; ++mf) {
                const int row = wm * 32 + mf * 16 + r;
                bf16x8 a = *reinterpret_cast<const bf16x8*>(
                    &As[row * 64 + (((kk << 2) + g) ^ (r & 7)) * 8]);
                #pragma unroll
                for (int nf = 0; nf < 4; ++nf)
                    acc[mf][nf] = __builtin_amdgcn_mfma_f32_16x16x32_bf16(a, bfrag[nf], acc[mf][nf], 0, 0, 0);
            }
        }
    }

    #pragma unroll
    for (int mf = 0; mf < 2; ++mf)
        #pragma unroll
        for (int nf = 0; nf < 4; ++nf)
            #pragma unroll
            for (int j = 0; j < 4; ++j) {
                const int row = rowBase + wm * 32 + mf * 16 + g * 4 + j;
                const int col = colBase + wn * 64 + nf * 16 + r;
                C[(size_t)row * N + col] = acc[mf][nf][j];
            }
}

// ============================================================================
// MFMA retention (R6 proven version, reverted from failed 4x4-PV). 1D grid of
// 512, XCD-pinned: h = bid&7. Mask on the fly; K/V staged via global_load_lds,
// XOR-swizzled (rule #21). Per-wave Ps: QK and PV independent across waves,
// only 2 barriers/iter.
// ============================================================================
__global__ __launch_bounds__(256)
void retention_mfma(const __bf16* __restrict__ Qb, const __bf16* __restrict__ Kb,
                    const __bf16* __restrict__ Vt,
                    const __bf16* __restrict__ Gb, __bf16* __restrict__ Yb) {
    const int tid = threadIdx.x;
    const int w = tid >> 6, lane = tid & 63;
    const int g = lane >> 4, r = lane & 15;
    const int rx = r & 7;
    const int bid = blockIdx.x;
    const int h = bid & 7;
    const int slot = bid >> 3;
    const int b = slot & 1;
    const int x = slot >> 1;
    const int qt = (b == 0) ? (31 - x) : x;
    const int tt0 = qt * 64;
    const int trow0 = w * 16;

    __shared__ __align__(16) __bf16 Ks[64][128];   // linear, swizzled content
    __shared__ __align__(16) __bf16 Vs[256][64];   // linear, swizzled content
    __shared__ __align__(16) __bf16 Ps[4][16][72]; // per-wave P tile, +8 pad

    // ---- decay constants (mask on the fly) ----
    const float rho   = 1.0f - exp2f(-(float)(5 + h));
    const float l2r   = log2f(rho);
    const float inv1m = exp2f((float)(5 + h));      // 1/(1-rho)
    int   tj[4];
    float nrm[4];
    #pragma unroll
    for (int j = 0; j < 4; ++j) {
        tj[j] = tt0 + trow0 + g * 4 + j;
        nrm[j] = rsqrtf((1.0f - exp2f(l2r * (float)(tj[j] + 1))) * inv1m);
    }
    float pneg[4];                                  // rho^(-(ssub*16+r))
    #pragma unroll
    for (int ssub = 0; ssub < 4; ++ssub)
        pneg[ssub] = exp2f(-l2r * (float)(ssub * 16 + r));

    // Q fragments: wave's 16 q-rows x 128 k, persistent in registers
    bf16x8 qf[4];
    {
        const __bf16* qrow = Qb + ((size_t)(b * T_SEQ + tt0 + trow0 + r)) * EMBED + h * KDIM;
        #pragma unroll
        for (int kb = 0; kb < 4; ++kb)
            qf[kb] = *reinterpret_cast<const bf16x8*>(qrow + kb * 32 + g * 8);
    }

    f32x4 acc[16];
    #pragma unroll
    for (int db = 0; db < 16; ++db) acc[db] = (f32x4){0.f, 0.f, 0.f, 0.f};
    float dsum[4] = {0.f, 0.f, 0.f, 0.f};

    const __bf16* vtbase = Vt + ((size_t)(b * NHEADS + h) * HDIM) * T_SEQ;
    const __bf16* kbase  = Kb + ((size_t)(b * T_SEQ)) * EMBED + h * KDIM;

    // staging maps (per-lane source offsets)
    const int klr = lane >> 4;                      // K: row within 4-row call
    const int kc  = lane & 15;
    const int kswz_even = (kc ^ klr) * 8;           // cc even
    const int kswz_odd  = (kc ^ (4 + klr)) * 8;     // cc odd
    const int vlr  = lane >> 3;                     // V: row within 8-row call
    const int vswz = ((lane & 7) ^ vlr) * 8;

    const int nS = qt + 1;
    for (int st = 0; st < nS; ++st) {
        const int ss0 = st * 64;
        __syncthreads();  // previous tile's LDS reads complete
        // ---- K s-tile 64x128: 16 calls (4/wave)
        #pragma unroll
        for (int p = 0; p < 4; ++p) {
            const int cc = 4 * w + p;
            const int se = (p & 1) ? kswz_odd : kswz_even;
            gload16(kbase + (size_t)(ss0 + 4 * cc + klr) * EMBED + se,
                    (char*)&Ks[0][0] + cc * 1024);
        }
        // ---- V^T s-tile 256x64: 32 calls (8/wave)
        #pragma unroll
        for (int p = 0; p < 8; ++p) {
            const int cc = 8 * w + p;
            gload16(vtbase + (size_t)(8 * cc + vlr) * T_SEQ + ss0 + vswz,
                    (char*)&Vs[0][0] + cc * 1024);
        }
        __syncthreads();  // all gload_lds writes landed (vmcnt drain)

        // per-tile decay factors
        float wj[4];
        #pragma unroll
        for (int j = 0; j < 4; ++j)
            wj[j] = exp2f(l2r * (float)(tj[j] - ss0)) * nrm[j];
        const bool diag = (st == qt);

        // ---- QK^T + mask + dsum + P->LDS (4 s-subtiles of 16) ----
        #pragma unroll
        for (int ssub = 0; ssub < 4; ++ssub) {
            f32x4 sacc = (f32x4){0.f, 0.f, 0.f, 0.f};
            #pragma unroll
            for (int kb = 0; kb < 4; ++kb) {
                bf16x8 kf = *reinterpret_cast<const bf16x8*>(
                    &Ks[ssub * 16 + r][((kb * 4 + g) ^ rx) * 8]);
                sacc = __builtin_amdgcn_mfma_f32_16x16x32_bf16(qf[kb], kf, sacc, 0, 0, 0);
            }
            const int scol = ss0 + ssub * 16 + r;
            const float mfac = pneg[ssub];
            #pragma unroll
            for (int j = 0; j < 4; ++j) {
                float pv = sacc[j] * (wj[j] * mfac);
                if (diag && scol > tj[j]) pv = 0.f;
                dsum[j] += fabsf(pv);
                Ps[w][g * 4 + j][ssub * 16 + r] = (__bf16)pv;
            }
        }

        // ---- PV: acc[db] += P(16x64) @ V^T(256x64)^T ----
        #pragma unroll
        for (int sh = 0; sh < 2; ++sh) {
            bf16x8 pf = *reinterpret_cast<const bf16x8*>(&Ps[w][r][sh * 32 + g * 8]);
            #pragma unroll
            for (int db = 0; db < 16; ++db) {
                bf16x8 vf = *reinterpret_cast<const bf16x8*>(
                    &Vs[db * 16 + r][((sh * 4 + g) ^ rx) * 8]);
                acc[db] = __builtin_amdgcn_mfma_f32_16x16x32_bf16(pf, vf, acc[db], 0, 0, 0);
            }
        }
    }

    // ---- epilogue ----
    #pragma unroll
    for (int j = 0; j < 4; ++j) {
        float v = dsum[j];
        v += __shfl_xor(v, 1); v += __shfl_xor(v, 2);
        v += __shfl_xor(v, 4); v += __shfl_xor(v, 8);
        dsum[j] = fminf(fmaxf(v, 1.0f), 50000.0f);
    }
    float ss[4] = {0.f, 0.f, 0.f, 0.f};
    #pragma unroll
    for (int db = 0; db < 16; ++db)
        #pragma unroll
        for (int j = 0; j < 4; ++j) {
            const float v = acc[db][j] / dsum[j];
            acc[db][j] = v;
            ss[j] = fmaf(v, v, ss[j]);
        }
    #pragma unroll
    for (int j = 0; j < 4; ++j) {
        float v = ss[j];
        v += __shfl_xor(v, 1); v += __shfl_xor(v, 2);
        v += __shfl_xor(v, 4); v += __shfl_xor(v, 8);
        ss[j] = rsqrtf(v * (1.0f / 256.0f) + EPS);
    }
    #pragma unroll
    for (int j = 0; j < 4; ++j) {
        const size_t row = (size_t)(b * T_SEQ + tj[j]);
        const __bf16* grow = Gb + row * VDIM + h * HDIM;
        __bf16* yrow = Yb + row * VDIM + h * HDIM;
        #pragma unroll
        for (int db = 0; db < 16; ++db) {
            const int c = db * 16 + r;
            const float gv = (float)grow[c];
            const float sil = gv / (1.0f + expf(-gv));
            yrow[c] = (__bf16)(sil * acc[db][j] * ss[j]);
        }
    }
}

// ============================================================================
// launch
// ============================================================================
extern "C" void kernel_launch(void* const* d_in, const int* in_sizes, int n_in,
                              void* d_out, int out_size, void* d_ws, size_t ws_size,
                              hipStream_t stream) {
    (void)in_sizes; (void)n_in; (void)out_size; (void)ws_size;

    const float* x    = (const float*)d_in[0];
    const float* sinT = (const float*)d_in[1];
    const float* cosT = (const float*)d_in[2];
    // d_in[3] (mask) is recomputed on the fly in retention_mfma
    const float* Wq   = (const float*)d_in[4];
    const float* Wk   = (const float*)d_in[5];
    const float* Wv   = (const float*)d_in[6];
    const float* Wg   = (const float*)d_in[7];
    const float* Wo   = (const float*)d_in[8];
    float* out = (float*)d_out;

    // workspace layout (bytes), peak 88 MB. WqT..WgT are CONTIGUOUS -> one
    // packed [6144][1024] weight matrix for the fused projection GEMM.
    char* wsp = (char*)d_ws;
    __bf16* xb  = (__bf16*)(wsp);
    __bf16* WqT = (__bf16*)(wsp + (8u  << 20));
    __bf16* WkT = (__bf16*)(wsp + (10u << 20));
    __bf16* WvT = (__bf16*)(wsp + (12u << 20));
    __bf16* WgT = (__bf16*)(wsp + (16u << 20));
    __bf16* WoT = (__bf16*)(wsp + (20u << 20));
    __bf16* Qb  = (__bf16*)(wsp + (24u << 20));
    __bf16* Kb  = (__bf16*)(wsp + (32u << 20));
    __bf16* Yb  = (__bf16*)(wsp + (40u << 20));  // retention output (gated)
    __bf16* Gb  = (__bf16*)(wsp + (56u << 20));
    __bf16* Vt  = (__bf16*)(wsp + (72u << 20));
    __bf16* WTall = WqT;                         // packed Q|K|V|G weights

    const dim3 blk(256);
    const dim3 tblk(32, 8);

    // ---- prep (merged transposes + x convert) ----
    prep_all<<<12288, tblk, 0, stream>>>(x, Wq, Wk, Wv, Wg, Wo,
                                         xb, WqT, WkT, WvT, WgT, WoT);

    // ---- fused QKVG projection (rotation + kscale + V-transpose in epilogue)
    gemm_qkvg<<<1536, blk, 0, stream>>>(xb, WTall, Qb, Kb, Vt, Gb, sinT, cosT);

    // ---- fused retention (MFMA, mask on the fly, XCD-pinned) ----
    retention_mfma<<<512, blk, 0, stream>>>(Qb, Kb, Vt, Gb, Yb);

    // ---- output projection ----
    gemm_wo<<<512, blk, 0, stream>>>(Yb, WoT, out);
}

// Round 11
// 191.504 us; speedup vs baseline: 1.2783x; 1.0166x over previous
//
#include <hip/hip_runtime.h>
#include <hip/hip_bf16.h>
#include <math.h>

// ---- problem constants (MultiScaleRetention, B=2,T=2048,E=1024,V=2048,H=8) ----
constexpr int T_SEQ = 2048;
constexpr int BB    = 2;
constexpr int EMBED = 1024;
constexpr int VDIM  = 2048;
constexpr int NHEADS = 8;
constexpr int KDIM  = 128;
constexpr int HDIM  = 256;
constexpr int ROWS  = BB * T_SEQ;  // 4096
constexpr int NALL  = 6144;        // Q(1024)+K(1024)+V(2048)+G(2048)
constexpr float EPS = 1e-6f;

typedef float  f32x4  __attribute__((ext_vector_type(4)));
typedef __bf16 bf16x8 __attribute__((ext_vector_type(8)));
typedef __bf16 bf16x4 __attribute__((ext_vector_type(4)));

// async global->LDS, 16B per lane. LDS dest is wave-uniform base + lane*16;
// global src is per-lane.
__device__ __forceinline__ void gload16(const void* g, void* l) {
    __builtin_amdgcn_global_load_lds(
        (__attribute__((address_space(1))) void*)g,
        (__attribute__((address_space(3))) void*)l, 16, 0, 0);
}

#define WAITV(n) asm volatile("s_waitcnt vmcnt(" #n ")" ::: "memory")
#define BARRIER() __builtin_amdgcn_s_barrier()

// ============================================================================
// Merged prep: five W[K][N] f32 -> WT[N][K] bf16 transposes (bid < 8192)
// + x f32->bf16 convert (bid >= 8192). One launch.
// ============================================================================
__global__ __launch_bounds__(256)
void prep_all(const float* __restrict__ x, const float* __restrict__ Wq,
              const float* __restrict__ Wk, const float* __restrict__ Wv,
              const float* __restrict__ Wg, const float* __restrict__ Wo,
              __bf16* __restrict__ xb,
              __bf16* __restrict__ WqT, __bf16* __restrict__ WkT,
              __bf16* __restrict__ WvT, __bf16* __restrict__ WgT,
              __bf16* __restrict__ WoT) {
    const int bid = blockIdx.x;
    const int x_ = threadIdx.x, y_ = threadIdx.y;
    if (bid >= 8192) {
        const int i = (bid - 8192) * 256 + y_ * 32 + x_;
        float4 v = reinterpret_cast<const float4*>(x)[i];
        bf16x4 o = { (__bf16)v.x, (__bf16)v.y, (__bf16)v.z, (__bf16)v.w };
        reinterpret_cast<bf16x4*>(xb)[i] = o;
        return;
    }
    const float* W; __bf16* WT; int K, N, cx, cy;
    if (bid < 1024)      { W = Wq; WT = WqT; K = 1024; N = 1024; int rm = bid;        cx = rm & 31; cy = rm >> 5; }
    else if (bid < 2048) { W = Wk; WT = WkT; K = 1024; N = 1024; int rm = bid - 1024; cx = rm & 31; cy = rm >> 5; }
    else if (bid < 4096) { W = Wv; WT = WvT; K = 1024; N = 2048; int rm = bid - 2048; cx = rm & 63; cy = rm >> 6; }
    else if (bid < 6144) { W = Wg; WT = WgT; K = 1024; N = 2048; int rm = bid - 4096; cx = rm & 63; cy = rm >> 6; }
    else                 { W = Wo; WT = WoT; K = 2048; N = 1024; int rm = bid - 6144; cx = rm & 31; cy = rm >> 5; }

    __shared__ float tile[32][33];
    const int c0 = cx * 32, k0 = cy * 32;
    #pragma unroll
    for (int p = 0; p < 4; ++p)
        tile[y_ + p * 8][x_] = W[(size_t)(k0 + y_ + p * 8) * N + c0 + x_];
    __syncthreads();
    #pragma unroll
    for (int p = 0; p < 4; ++p)
        WT[(size_t)(c0 + y_ + p * 8) * K + k0 + x_] = (__bf16)tile[x_][y_ + p * 8];
}

// ============================================================================
// Fused QKVG projection GEMM (unchanged from R10 — measured plateau ~90us):
// C = xb @ WTall^T, segment-routed; RoPE+kscale in epilogue; V written
// transposed to Vt via per-wave LDS turn. m97 2-barrier, 128x128, BK=64,
// G4 both-sides swizzle, row-pinned XCD swizzle.
// ============================================================================
__global__ __launch_bounds__(256)
void gemm_qkvg(const __bf16* __restrict__ A, const __bf16* __restrict__ BT,
               __bf16* __restrict__ Qb, __bf16* __restrict__ Kb,
               __bf16* __restrict__ Vt, __bf16* __restrict__ Gb,
               const float* __restrict__ sinT, const float* __restrict__ cosT) {
    constexpr int K = EMBED;
    __shared__ __align__(16) char smem[36864];
    __bf16* As = (__bf16*)smem;               // [128][64] linear, swizzled
    __bf16* Bs = (__bf16*)(smem + 16384);     // [128][64] linear, swizzled

    const int bid = blockIdx.x;
    const int swzb = (bid & 7) * 192 + (bid >> 3);
    const int rowBase = (swzb / 48) * 128;
    const int colBase = (swzb % 48) * 128;

    const int tid = threadIdx.x;
    const int w = tid >> 6, lane = tid & 63;
    const int g = lane >> 4, r = lane & 15;
    const int wm = w >> 1, wn = w & 1;

    const int vr  = lane >> 3;
    const int swz = ((lane & 7) ^ vr) * 8;
    const __bf16* aSb = A  + (size_t)(rowBase + 32 * w + vr) * K + swz;
    const __bf16* bSb = BT + (size_t)(colBase + 32 * w + vr) * K + swz;

    f32x4 acc[4][4];
    #pragma unroll
    for (int i = 0; i < 4; ++i)
        #pragma unroll
        for (int j = 0; j < 4; ++j)
            acc[i][j] = (f32x4){0.f, 0.f, 0.f, 0.f};

    for (int k0 = 0; k0 < K; k0 += 64) {
        __syncthreads();
        #pragma unroll
        for (int p = 0; p < 4; ++p) {
            const int cc = 4 * w + p;
            gload16(aSb + (size_t)(8 * p) * K + k0, smem         + cc * 1024);
            gload16(bSb + (size_t)(8 * p) * K + k0, smem + 16384 + cc * 1024);
        }
        __syncthreads();

        #pragma unroll
        for (int kk = 0; kk < 2; ++kk) {
            bf16x8 bfrag[4];
            #pragma unroll
            for (int nf = 0; nf < 4; ++nf) {
                const int row = wn * 64 + nf * 16 + r;
                bfrag[nf] = *reinterpret_cast<const bf16x8*>(
                    &Bs[row * 64 + (((kk << 2) + g) ^ (r & 7)) * 8]);
            }
            #pragma unroll
            for (int mf = 0; mf < 4; ++mf) {
                const int row = wm * 64 + mf * 16 + r;
                bf16x8 a = *reinterpret_cast<const bf16x8*>(
                    &As[row * 64 + (((kk << 2) + g) ^ (r & 7)) * 8]);
                #pragma unroll
                for (int nf = 0; nf < 4; ++nf)
                    acc[mf][nf] = __builtin_amdgcn_mfma_f32_16x16x32_bf16(a, bfrag[nf], acc[mf][nf], 0, 0, 0);
            }
        }
    }

    constexpr float kscale = 0.08838834764831845f;  // KEY_DIM^-0.5
    if (colBase >= 2048 && colBase < 4096) {
        // V segment: transposed write to Vt[b][h][d][t]
        __syncthreads();
        __bf16* Es = (__bf16*)smem + w * (64 * 72);
        #pragma unroll
        for (int mf = 0; mf < 4; ++mf)
            #pragma unroll
            for (int nf = 0; nf < 4; ++nf) {
                bf16x4 v = { (__bf16)acc[mf][nf][0], (__bf16)acc[mf][nf][1],
                             (__bf16)acc[mf][nf][2], (__bf16)acc[mf][nf][3] };
                *reinterpret_cast<bf16x4*>(&Es[(nf * 16 + r) * 72 + mf * 16 + g * 4]) = v;
            }
        __syncthreads();
        const int t0g = rowBase + wm * 64;
        const int bq = t0g >> 11, tl = t0g & 2047;
        const int colV0 = (colBase - 2048) + wn * 64;
        const int h = colV0 >> 8, dd0 = colV0 & 255;
        const int li = lane & 7, rgrp = lane >> 3;
        __bf16* vtb = Vt + ((size_t)(bq * NHEADS + h) * HDIM + dd0) * T_SEQ + tl;
        #pragma unroll
        for (int c = 0; c < 8; ++c) {
            const int drow = 8 * c + rgrp;
            bf16x8 v = *reinterpret_cast<const bf16x8*>(&Es[drow * 72 + li * 8]);
            *reinterpret_cast<bf16x8*>(vtb + (size_t)drow * T_SEQ + li * 8) = v;
        }
        return;
    }

    __bf16* dst; int dstride, cofs; float alphaSeg; bool rot;
    if (colBase < 1024)      { dst = Qb; dstride = 1024; cofs = colBase;        alphaSeg = 1.0f;   rot = true;  }
    else if (colBase < 2048) { dst = Kb; dstride = 1024; cofs = colBase - 1024; alphaSeg = kscale; rot = true;  }
    else                     { dst = Gb; dstride = 2048; cofs = colBase - 4096; alphaSeg = 1.0f;   rot = false; }

    #pragma unroll
    for (int mf = 0; mf < 4; ++mf)
        #pragma unroll
        for (int nf = 0; nf < 4; ++nf)
            #pragma unroll
            for (int j = 0; j < 4; ++j) {
                const int row  = rowBase + wm * 64 + mf * 16 + g * 4 + j;
                const int colL = cofs + wn * 64 + nf * 16 + r;
                float v = acc[mf][nf][j] * alphaSeg;
                if (rot) {
                    const float p = __shfl_xor(v, 1);
                    const int t  = row & (T_SEQ - 1);
                    const int dh = colL & (KDIM - 1);
                    const float c = cosT[t * KDIM + dh];
                    const float s = sinT[t * KDIM + dh];
                    v = (r & 1) ? (v * c + p * s) : (v * c - p * s);
                }
                dst[(size_t)row * dstride + colL] = (__bf16)v;
            }
}

// ============================================================================
// Output projection (unchanged from R10): 64x128 tile, BK=64, 2-barrier,
// row-pinned XCD swizzle, G4 swizzle.
// ============================================================================
__global__ __launch_bounds__(256)
void gemm_wo(const __bf16* __restrict__ A, const __bf16* __restrict__ BT,
             float* __restrict__ C) {
    constexpr int N = EMBED, K = VDIM;
    __shared__ __align__(16) char smem[24576];
    __bf16* As = (__bf16*)smem;               // [64][64]
    __bf16* Bs = (__bf16*)(smem + 8192);      // [128][64]

    const int bid = blockIdx.x;
    const int swzb = (bid & 7) * 64 + (bid >> 3);
    const int rowBase = (swzb >> 3) * 64;
    const int colBase = (swzb & 7) * 128;

    const int tid = threadIdx.x;
    const int w = tid >> 6, lane = tid & 63;
    const int g = lane >> 4, r = lane & 15;
    const int wm = w >> 1, wn = w & 1;

    const int vr  = lane >> 3;
    const int swz = ((lane & 7) ^ vr) * 8;
    const __bf16* aSb = A  + (size_t)(rowBase + 16 * w + vr) * K + swz;
    const __bf16* bSb = BT + (size_t)(colBase + 32 * w + vr) * K + swz;

    f32x4 acc[2][4];
    #pragma unroll
    for (int i = 0; i < 2; ++i)
        #pragma unroll
        for (int j = 0; j < 4; ++j)
            acc[i][j] = (f32x4){0.f, 0.f, 0.f, 0.f};

    for (int k0 = 0; k0 < K; k0 += 64) {
        __syncthreads();
        #pragma unroll
        for (int p = 0; p < 2; ++p) {
            const int cc = 2 * w + p;
            gload16(aSb + (size_t)(8 * p) * K + k0, smem + cc * 1024);
        }
        #pragma unroll
        for (int p = 0; p < 4; ++p) {
            const int cc = 4 * w + p;
            gload16(bSb + (size_t)(8 * p) * K + k0, smem + 8192 + cc * 1024);
        }
        __syncthreads();

        #pragma unroll
        for (int kk = 0; kk < 2; ++kk) {
            bf16x8 bfrag[4];
            #pragma unroll
            for (int nf = 0; nf < 4; ++nf) {
                const int row = wn * 64 + nf * 16 + r;
                bfrag[nf] = *reinterpret_cast<const bf16x8*>(
                    &Bs[row * 64 + (((kk << 2) + g) ^ (r & 7)) * 8]);
            }
            #pragma unroll
            for (int mf = 0; mf < 2; ++mf) {
                const int row = wm * 32 + mf * 16 + r;
                bf16x8 a = *reinterpret_cast<const bf16x8*>(
                    &As[row * 64 + (((kk << 2) + g) ^ (r & 7)) * 8]);
                #pragma unroll
                for (int nf = 0; nf < 4; ++nf)
                    acc[mf][nf] = __builtin_amdgcn_mfma_f32_16x16x32_bf16(a, bfrag[nf], acc[mf][nf], 0, 0, 0);
            }
        }
    }

    #pragma unroll
    for (int mf = 0; mf < 2; ++mf)
        #pragma unroll
        for (int nf = 0; nf < 4; ++nf)
            #pragma unroll
            for (int j = 0; j < 4; ++j) {
                const int row = rowBase + wm * 32 + mf * 16 + g * 4 + j;
                const int col = colBase + wn * 64 + nf * 16 + r;
                C[(size_t)row * N + col] = acc[mf][nf][j];
            }
}

// ============================================================================
// MFMA retention, pipelined staging (NEW):
//  - Ks double-buffered (K(t+1) issued during iter t, drained by next iter's
//    WAITV(0) after a full iteration in flight -> K latency fully hidden).
//  - V(t) issued at iter top; QK (which reads only Ks) runs between issue and
//    WAITV(4) -> V's L2 latency covered by ~400cy of MFMA+VALU.
//  - Raw s_barrier + explicit counted vmcnt (compiler emits no implicit
//    vmcnt(0) for raw barriers). 2 barriers/iter as before.
// Race safety: a wave passing barrier A implies all waves passed barrier B of
// the previous iter (QK(t-1) reads of Ks[cur^1] and PV(t-1) reads of Vs done)
// -> both staging targets free. Per-wave WAITV + barrier publishes gload-LDS.
// LDS 73 KB -> still 2 blocks/CU (same occupancy as R6/R10 version).
// ============================================================================
__global__ __launch_bounds__(256)
void retention_mfma(const __bf16* __restrict__ Qb, const __bf16* __restrict__ Kb,
                    const __bf16* __restrict__ Vt,
                    const __bf16* __restrict__ Gb, __bf16* __restrict__ Yb) {
    const int tid = threadIdx.x;
    const int w = tid >> 6, lane = tid & 63;
    const int g = lane >> 4, r = lane & 15;
    const int rx = r & 7;
    const int bid = blockIdx.x;
    const int h = bid & 7;
    const int slot = bid >> 3;
    const int b = slot & 1;
    const int x = slot >> 1;
    const int qt = (b == 0) ? (31 - x) : x;
    const int tt0 = qt * 64;
    const int trow0 = w * 16;

    __shared__ __align__(16) __bf16 Ks[2][64][128];  // 2x16KB, swizzled content
    __shared__ __align__(16) __bf16 Vs[256][64];     // 32KB, swizzled content
    __shared__ __align__(16) __bf16 Ps[4][16][72];   // per-wave P tile, +8 pad

    // ---- decay constants (mask on the fly) ----
    const float rho   = 1.0f - exp2f(-(float)(5 + h));
    const float l2r   = log2f(rho);
    const float inv1m = exp2f((float)(5 + h));      // 1/(1-rho)
    int   tj[4];
    float nrm[4];
    #pragma unroll
    for (int j = 0; j < 4; ++j) {
        tj[j] = tt0 + trow0 + g * 4 + j;
        nrm[j] = rsqrtf((1.0f - exp2f(l2r * (float)(tj[j] + 1))) * inv1m);
    }
    float pneg[4];                                  // rho^(-(ssub*16+r))
    #pragma unroll
    for (int ssub = 0; ssub < 4; ++ssub)
        pneg[ssub] = exp2f(-l2r * (float)(ssub * 16 + r));

    // Q fragments: wave's 16 q-rows x 128 k, persistent in registers
    bf16x8 qf[4];
    {
        const __bf16* qrow = Qb + ((size_t)(b * T_SEQ + tt0 + trow0 + r)) * EMBED + h * KDIM;
        #pragma unroll
        for (int kb = 0; kb < 4; ++kb)
            qf[kb] = *reinterpret_cast<const bf16x8*>(qrow + kb * 32 + g * 8);
    }

    f32x4 acc[16];
    #pragma unroll
    for (int db = 0; db < 16; ++db) acc[db] = (f32x4){0.f, 0.f, 0.f, 0.f};
    float dsum[4] = {0.f, 0.f, 0.f, 0.f};

    const __bf16* vtbase = Vt + ((size_t)(b * NHEADS + h) * HDIM) * T_SEQ;
    const __bf16* kbase  = Kb + ((size_t)(b * T_SEQ)) * EMBED + h * KDIM;

    // staging maps (per-lane source offsets)
    const int klr = lane >> 4;                      // K: row within 4-row call
    const int kc  = lane & 15;
    const int kswz_even = (kc ^ klr) * 8;           // cc even
    const int kswz_odd  = (kc ^ (4 + klr)) * 8;     // cc odd
    const int vlr  = lane >> 3;                     // V: row within 8-row call
    const int vswz = ((lane & 7) ^ vlr) * 8;

    // ---- prologue: issue K(0) -> Ks[0] ----
    #pragma unroll
    for (int p = 0; p < 4; ++p) {
        const int cc = 4 * w + p;
        const int se = (p & 1) ? kswz_odd : kswz_even;
        gload16(kbase + (size_t)(4 * cc + klr) * EMBED + se,
                (char*)&Ks[0][0][0] + cc * 1024);
    }

    int cur = 0;
    const int nS = qt + 1;
    for (int st = 0; st < nS; ++st) {
        const int ss0 = st * 64;
        WAITV(0);        // K(st) landed (in flight for a full iteration: free)
        BARRIER();       // A: K(st) visible; Vs(t-1)/Ks[cur^1] reads all done

        // ---- issue V(st) -> Vs (8 calls) ----
        #pragma unroll
        for (int p = 0; p < 8; ++p) {
            const int cc = 8 * w + p;
            gload16(vtbase + (size_t)(8 * cc + vlr) * T_SEQ + ss0 + vswz,
                    (char*)&Vs[0][0] + cc * 1024);
        }
        // ---- issue K(st+1) -> Ks[cur^1] (4 calls, stays in flight) ----
        const bool more = (st + 1 < nS);
        if (more) {
            const int ssn = ss0 + 64;
            #pragma unroll
            for (int p = 0; p < 4; ++p) {
                const int cc = 4 * w + p;
                const int se = (p & 1) ? kswz_odd : kswz_even;
                gload16(kbase + (size_t)(ssn + 4 * cc + klr) * EMBED + se,
                        (char*)&Ks[cur ^ 1][0][0] + cc * 1024);
            }
        }

        // per-tile decay factors
        float wj[4];
        #pragma unroll
        for (int j = 0; j < 4; ++j)
            wj[j] = exp2f(l2r * (float)(tj[j] - ss0)) * nrm[j];
        const bool diag = (st == qt);

        // ---- QK^T from Ks[cur] (no Vs dependency — covers V latency) ----
        #pragma unroll
        for (int ssub = 0; ssub < 4; ++ssub) {
            f32x4 sacc = (f32x4){0.f, 0.f, 0.f, 0.f};
            #pragma unroll
            for (int kb = 0; kb < 4; ++kb) {
                bf16x8 kf = *reinterpret_cast<const bf16x8*>(
                    &Ks[cur][ssub * 16 + r][((kb * 4 + g) ^ rx) * 8]);
                sacc = __builtin_amdgcn_mfma_f32_16x16x32_bf16(qf[kb], kf, sacc, 0, 0, 0);
            }
            const int scol = ss0 + ssub * 16 + r;
            const float mfac = pneg[ssub];
            #pragma unroll
            for (int j = 0; j < 4; ++j) {
                float pv = sacc[j] * (wj[j] * mfac);
                if (diag && scol > tj[j]) pv = 0.f;
                dsum[j] += fabsf(pv);
                Ps[w][g * 4 + j][ssub * 16 + r] = (__bf16)pv;
            }
        }

        if (more) { WAITV(4); }   // V(st) landed; K(st+1) stays in flight
        else      { WAITV(0); }
        BARRIER();                // B: all waves' V(st) visible

        // ---- PV: acc[db] += P(16x64) @ V^T(256x64)^T ----
        #pragma unroll
        for (int sh = 0; sh < 2; ++sh) {
            bf16x8 pf = *reinterpret_cast<const bf16x8*>(&Ps[w][r][sh * 32 + g * 8]);
            #pragma unroll
            for (int db = 0; db < 16; ++db) {
                bf16x8 vf = *reinterpret_cast<const bf16x8*>(
                    &Vs[db * 16 + r][((sh * 4 + g) ^ rx) * 8]);
                acc[db] = __builtin_amdgcn_mfma_f32_16x16x32_bf16(pf, vf, acc[db], 0, 0, 0);
            }
        }
        cur ^= 1;
    }

    // ---- epilogue ----
    #pragma unroll
    for (int j = 0; j < 4; ++j) {
        float v = dsum[j];
        v += __shfl_xor(v, 1); v += __shfl_xor(v, 2);
        v += __shfl_xor(v, 4); v += __shfl_xor(v, 8);
        dsum[j] = fminf(fmaxf(v, 1.0f), 50000.0f);
    }
    float ss[4] = {0.f, 0.f, 0.f, 0.f};
    #pragma unroll
    for (int db = 0; db < 16; ++db)
        #pragma unroll
        for (int j = 0; j < 4; ++j) {
            const float v = acc[db][j] / dsum[j];
            acc[db][j] = v;
            ss[j] = fmaf(v, v, ss[j]);
        }
    #pragma unroll
    for (int j = 0; j < 4; ++j) {
        float v = ss[j];
        v += __shfl_xor(v, 1); v += __shfl_xor(v, 2);
        v += __shfl_xor(v, 4); v += __shfl_xor(v, 8);
        ss[j] = rsqrtf(v * (1.0f / 256.0f) + EPS);
    }
    #pragma unroll
    for (int j = 0; j < 4; ++j) {
        const size_t row = (size_t)(b * T_SEQ + tj[j]);
        const __bf16* grow = Gb + row * VDIM + h * HDIM;
        __bf16* yrow = Yb + row * VDIM + h * HDIM;
        #pragma unroll
        for (int db = 0; db < 16; ++db) {
            const int c = db * 16 + r;
            const float gv = (float)grow[c];
            const float sil = gv / (1.0f + expf(-gv));
            yrow[c] = (__bf16)(sil * acc[db][j] * ss[j]);
        }
    }
}

// ============================================================================
// launch
// ============================================================================
extern "C" void kernel_launch(void* const* d_in, const int* in_sizes, int n_in,
                              void* d_out, int out_size, void* d_ws, size_t ws_size,
                              hipStream_t stream) {
    (void)in_sizes; (void)n_in; (void)out_size; (void)ws_size;

    const float* x    = (const float*)d_in[0];
    const float* sinT = (const float*)d_in[1];
    const float* cosT = (const float*)d_in[2];
    // d_in[3] (mask) is recomputed on the fly in retention_mfma
    const float* Wq   = (const float*)d_in[4];
    const float* Wk   = (const float*)d_in[5];
    const float* Wv   = (const float*)d_in[6];
    const float* Wg   = (const float*)d_in[7];
    const float* Wo   = (const float*)d_in[8];
    float* out = (float*)d_out;

    // workspace layout (bytes), peak 88 MB. WqT..WgT are CONTIGUOUS -> one
    // packed [6144][1024] weight matrix for the fused projection GEMM.
    char* wsp = (char*)d_ws;
    __bf16* xb  = (__bf16*)(wsp);
    __bf16* WqT = (__bf16*)(wsp + (8u  << 20));
    __bf16* WkT = (__bf16*)(wsp + (10u << 20));
    __bf16* WvT = (__bf16*)(wsp + (12u << 20));
    __bf16* WgT = (__bf16*)(wsp + (16u << 20));
    __bf16* WoT = (__bf16*)(wsp + (20u << 20));
    __bf16* Qb  = (__bf16*)(wsp + (24u << 20));
    __bf16* Kb  = (__bf16*)(wsp + (32u << 20));
    __bf16* Yb  = (__bf16*)(wsp + (40u << 20));  // retention output (gated)
    __bf16* Gb  = (__bf16*)(wsp + (56u << 20));
    __bf16* Vt  = (__bf16*)(wsp + (72u << 20));
    __bf16* WTall = WqT;                         // packed Q|K|V|G weights

    const dim3 blk(256);
    const dim3 tblk(32, 8);

    // ---- prep (merged transposes + x convert) ----
    prep_all<<<12288, tblk, 0, stream>>>(x, Wq, Wk, Wv, Wg, Wo,
                                         xb, WqT, WkT, WvT, WgT, WoT);

    // ---- fused QKVG projection (rotation + kscale + V-transpose in epilogue)
    gemm_qkvg<<<1536, blk, 0, stream>>>(xb, WTall, Qb, Kb, Vt, Gb, sinT, cosT);

    // ---- fused retention (MFMA, mask on the fly, XCD-pinned, pipelined) ----
    retention_mfma<<<512, blk, 0, stream>>>(Qb, Kb, Vt, Gb, Yb);

    // ---- output projection ----
    gemm_wo<<<512, blk, 0, stream>>>(Yb, WoT, out);
}